// Round 4
// baseline (582.306 us; speedup 1.0000x reference)
//
#include <hip/hip_runtime.h>

#define H 512
#define W 512
#define NEG_HUGE (-3.402823466e38f)

__global__ void zero_acc_kernel(double* acc) {
    if (threadIdx.x == 0) acc[0] = 0.0;
}

// One block per (row, image). Computes s = 3x3 avg (zero pad, /9) for this row
// into LDS, then 17-wide horizontal sliding max & sum -> hmax/hsum.
__global__ __launch_bounds__(256) void hpass_kernel(const float* __restrict__ in,
                                                    float* __restrict__ hmax,
                                                    float* __restrict__ hsum) {
    const int y   = blockIdx.x;
    const int img = blockIdx.y;
    const float* im = in + (size_t)img * H * W;

    __shared__ float srow[W];

    for (int x = threadIdx.x; x < W; x += 256) {
        float a = 0.f;
#pragma unroll
        for (int dy = -1; dy <= 1; ++dy) {
            int yy = y + dy;
            if (yy < 0 || yy >= H) continue;
            const float* r = im + yy * W;
#pragma unroll
            for (int dx = -1; dx <= 1; ++dx) {
                int xx = x + dx;
                if (xx >= 0 && xx < W) a += r[xx];
            }
        }
        srow[x] = a * (1.f / 9.f);
    }
    __syncthreads();

    float* om = hmax + ((size_t)img * H + y) * W;
    float* os = hsum + ((size_t)img * H + y) * W;
    for (int x = threadIdx.x; x < W; x += 256) {
        float m = NEG_HUGE;
        float s = 0.f;
#pragma unroll
        for (int dx = -8; dx <= 8; ++dx) {
            int xx = x + dx;
            if (xx >= 0 && xx < W) {
                float v = srow[xx];
                m = fmaxf(m, v);
                s += v;
            }
        }
        om[x] = m;
        os[x] = s;
    }
}

// One block per (row, image). 17-tall vertical max over hmax and sum over hsum,
// then accumulate sum of (max - sum/289) into acc.
__global__ __launch_bounds__(256) void vpass_kernel(const float* __restrict__ hmax,
                                                    const float* __restrict__ hsum,
                                                    double* __restrict__ acc) {
    const int y   = blockIdx.x;
    const int img = blockIdx.y;
    const float* bm = hmax + (size_t)img * H * W;
    const float* bs = hsum + (size_t)img * H * W;

    float local = 0.f;
    for (int x = threadIdx.x; x < W; x += 256) {
        float m = NEG_HUGE;
        float s = 0.f;
#pragma unroll
        for (int dy = -8; dy <= 8; ++dy) {
            int yy = y + dy;
            if (yy >= 0 && yy < H) {
                m = fmaxf(m, bm[yy * W + x]);
                s += bs[yy * W + x];
            }
        }
        local += m - s * (1.f / 289.f);
    }

    // wave reduce (64 lanes)
    double v = (double)local;
#pragma unroll
    for (int off = 32; off > 0; off >>= 1)
        v += __shfl_down(v, off, 64);

    __shared__ double wsum[4];
    int lane = threadIdx.x & 63;
    int wave = threadIdx.x >> 6;
    if (lane == 0) wsum[wave] = v;
    __syncthreads();
    if (threadIdx.x == 0) {
        double b = wsum[0] + wsum[1] + wsum[2] + wsum[3];
        atomicAdd(acc, b);
    }
}

__global__ void finalize_kernel(const double* __restrict__ acc, float* __restrict__ out) {
    if (threadIdx.x == 0) {
        // total pixels across both tensors = 2*32*512*512 = 16777216
        out[0] = (float)(1.0 - acc[0] * (1.0 / 16777216.0));
    }
}

extern "C" void kernel_launch(void* const* d_in, const int* in_sizes, int n_in,
                              void* d_out, int out_size, void* d_ws, size_t ws_size,
                              hipStream_t stream) {
    const float* in0 = (const float*)d_in[0];
    const float* in1 = (const float*)d_in[1];
    float* out = (float*)d_out;

    char* ws = (char*)d_ws;
    double* acc = (double*)ws;
    const size_t per_img = (size_t)H * W * sizeof(float); // 1 MB
    size_t avail = ws_size > 256 ? ws_size - 256 : 0;
    int cap = (int)(avail / (2 * per_img));
    if (cap > 32) cap = 32;
    if (cap < 1) cap = 1; // require at least ~2 MB of workspace
    float* hmax = (float*)(ws + 256);
    float* hsum = hmax + (size_t)cap * H * W;

    zero_acc_kernel<<<1, 64, 0, stream>>>(acc);

    for (int t = 0; t < 2; ++t) {
        const float* in = t ? in1 : in0;
        for (int c0 = 0; c0 < 32; c0 += cap) {
            int n = 32 - c0 < cap ? 32 - c0 : cap;
            hpass_kernel<<<dim3(H, n), 256, 0, stream>>>(in + (size_t)c0 * H * W, hmax, hsum);
            vpass_kernel<<<dim3(H, n), 256, 0, stream>>>(hmax, hsum, acc);
        }
    }

    finalize_kernel<<<1, 64, 0, stream>>>(acc, out);
}

// Round 5
// 265.640 us; speedup vs baseline: 2.1921x; 2.1921x over previous
//
#include <hip/hip_runtime.h>

#define H 512
#define W 512
#define BAND 64
#define NBANDS (H / BAND)  // 8

static __device__ __forceinline__ int imin(int a, int b) { return a < b ? a : b; }
static __device__ __forceinline__ int imax(int a, int b) { return a > b ? a : b; }

__global__ void zero_acc_kernel(double* acc) {
    if (threadIdx.x == 0) acc[0] = 0.0;
}

// One block per (band, image, tensor). Streams input rows once; computes
// s = 3x3 avg (zero-pad, /9) via rolling 3-row ring of horizontal 3-sums,
// 17-wide horizontal sliding max into a 17-row LDS ring, then 17-tall
// vertical max per output row. The avg-pool branch collapses to a weighted
// sum of s with closed-form border counts (no hsum storage needed).
__global__ __launch_bounds__(256) void fused_kernel(const float* __restrict__ in0,
                                                    const float* __restrict__ in1,
                                                    double* __restrict__ acc) {
    const int band = blockIdx.x;
    const int img  = blockIdx.y;
    const float* im = (blockIdx.z ? in1 : in0) + (size_t)img * H * W;

    const int y0  = band * BAND;
    const int y1  = y0 + BAND;
    const int jlo = imax(0, y0 - 8);
    const int jhi = imin(H - 1, y1 + 7);

    __shared__ float raw[W];        // current input row
    __shared__ float uring[3][W];   // horizontal 3-sums of last 3 input rows
    __shared__ float srow[W];       // current 3x3-avg row
    __shared__ float hring[17][W];  // last 17 h-pooled (17-wide max) rows
    __shared__ double wsum[4];

    const int tid = threadIdx.x;
    const int xa = tid;        // 0..255
    const int xb = tid + 256;  // 256..511

    // c(x)/289: number of horizontal windows covering column x, / k^2
    const float ca = (float)(imin(W - 1, xa + 8) - imax(0, xa - 8) + 1) * (1.f / 289.f);
    const float cb = (float)(imin(W - 1, xb + 8) - imax(0, xb - 8) + 1) * (1.f / 289.f);

    float accMax = 0.f, accSum = 0.f;

    // ---- prologue: u(jlo-1), u(jlo) ----
    for (int i = jlo - 1; i <= jlo; ++i) {
        float* u = uring[(i + 3) % 3];
        if (i >= 0) {
            raw[xa] = im[(size_t)i * W + xa];
            raw[xb] = im[(size_t)i * W + xb];
            __syncthreads();
            u[xa] = (xa > 0 ? raw[xa - 1] : 0.f) + raw[xa] + raw[xa + 1];
            u[xb] = raw[xb - 1] + raw[xb] + (xb < W - 1 ? raw[xb + 1] : 0.f);
            __syncthreads();
        } else {
            u[xa] = 0.f;  // row -1: zero padding
            u[xb] = 0.f;
        }
    }

    // ---- main loop over s-rows j ----
    int ynext = y0;
    for (int j = jlo; j <= jhi; ++j) {
        const int i = j + 1;  // input / u row to produce this iteration
        float* u2 = uring[i % 3];
        if (i < H) {
            raw[xa] = im[(size_t)i * W + xa];
            raw[xb] = im[(size_t)i * W + xb];
        }
        __syncthreads();  // A: raw ready; prev srow readers done
        if (i < H) {
            u2[xa] = (xa > 0 ? raw[xa - 1] : 0.f) + raw[xa] + raw[xa + 1];
            u2[xb] = raw[xb - 1] + raw[xb] + (xb < W - 1 ? raw[xb + 1] : 0.f);
        } else {
            u2[xa] = 0.f;
            u2[xb] = 0.f;
        }
        // s row j (same-column deps only, no sync needed)
        const float* u0 = uring[(j + 2) % 3];  // row j-1
        const float* u1 = uring[j % 3];        // row j
        srow[xa] = (u0[xa] + u1[xa] + u2[xa]) * (1.f / 9.f);
        srow[xb] = (u0[xb] + u1[xb] + u2[xb]) * (1.f / 9.f);
        __syncthreads();  // B: srow ready

        // 17-wide horizontal max -> hring (own-column writes)
        {
            const int lo = xa - 8 < 0 ? 0 : xa - 8;  // xa+8 <= 263 < W: no hi clamp
            float m = srow[lo];
            for (int xx = lo + 1; xx <= xa + 8; ++xx) m = fmaxf(m, srow[xx]);
            hring[j % 17][xa] = m;
        }
        {
            const int hi = xb + 8 > W - 1 ? W - 1 : xb + 8;  // xb-8 >= 248: no lo clamp
            float m = srow[xb - 8];
            for (int xx = xb - 8 + 1; xx <= hi; ++xx) m = fmaxf(m, srow[xx]);
            hring[j % 17][xb] = m;
        }

        // avg-pool branch: weighted sum of s (r(j) = rows in this band whose
        // vertical window covers j)
        {
            const int rlo = imax(y0, j - 8), rhi = imin(y1 - 1, j + 8);
            const float rj = (float)(rhi - rlo + 1);
            accSum += (srow[xa] * ca + srow[xb] * cb) * rj;
        }

        // emit output rows whose vertical window is complete
        while (ynext < y1 && (ynext + 8 <= j || j == H - 1)) {
            const int y = ynext;
            const int vlo = imax(0, y - 8), vhi = imin(H - 1, y + 8);
            float ma = hring[vlo % 17][xa];
            float mb = hring[vlo % 17][xb];
            for (int yy = vlo + 1; yy <= vhi; ++yy) {
                ma = fmaxf(ma, hring[yy % 17][xa]);
                mb = fmaxf(mb, hring[yy % 17][xb]);
            }
            accMax += ma + mb;
            ++ynext;
        }
    }

    // ---- block reduction ----
    double v = (double)(accMax - accSum);
#pragma unroll
    for (int off = 32; off > 0; off >>= 1) v += __shfl_down(v, off, 64);
    const int lane = tid & 63, wave = tid >> 6;
    if (lane == 0) wsum[wave] = v;
    __syncthreads();
    if (tid == 0) atomicAdd(acc, wsum[0] + wsum[1] + wsum[2] + wsum[3]);
}

__global__ void finalize_kernel(const double* __restrict__ acc, float* __restrict__ out) {
    if (threadIdx.x == 0) {
        // total pixels across both tensors = 2*32*512*512 = 16777216
        out[0] = (float)(1.0 - acc[0] * (1.0 / 16777216.0));
    }
}

extern "C" void kernel_launch(void* const* d_in, const int* in_sizes, int n_in,
                              void* d_out, int out_size, void* d_ws, size_t ws_size,
                              hipStream_t stream) {
    const float* in0 = (const float*)d_in[0];
    const float* in1 = (const float*)d_in[1];
    float* out = (float*)d_out;
    double* acc = (double*)d_ws;

    zero_acc_kernel<<<1, 64, 0, stream>>>(acc);
    fused_kernel<<<dim3(NBANDS, 32, 2), 256, 0, stream>>>(in0, in1, acc);
    finalize_kernel<<<1, 64, 0, stream>>>(acc, out);
}

// Round 6
// 100.738 us; speedup vs baseline: 5.7804x; 2.6369x over previous
//
#include <hip/hip_runtime.h>

#define H 512
#define W 512
#define BAND 64
#define NBANDS (H / BAND)   // 8
#define TMAX (BAND + 16)    // streamed rows per band (virtual included)
#define NEG_INF (-3.402823466e38f)

static __device__ __forceinline__ int imin(int a, int b) { return a < b ? a : b; }
static __device__ __forceinline__ int imax(int a, int b) { return a > b ? a : b; }

__global__ void zero_acc_kernel(double* acc) {
    if (threadIdx.x == 0) acc[0] = 0.0;
}

// One block per (band, image, tensor), 512 threads = 1 column each.
// Streams s-rows j = y0-8 .. y1+7 (virtual rows outside [0,H) give h=-inf).
// Horizontal 17-max: log-doubling in LDS (2,4,8,16 + combine), -inf left pad.
// Vertical 17-max: van Herk in registers (17-phase blocks, prefix P + suffix S_prev).
// Avg-pool branch collapses to weighted sum of s (closed-form border counts).
__global__ __launch_bounds__(512, 4) void fused_kernel(const float* __restrict__ in0,
                                                       const float* __restrict__ in1,
                                                       double* __restrict__ acc) {
    const int band = blockIdx.x;
    const int img  = blockIdx.y;
    const float* im = (blockIdx.z ? in1 : in0) + (size_t)img * H * W;

    const int y0    = band * BAND;
    const int y1    = y0 + BAND;
    const int jlo_v = y0 - 8;            // first streamed row (may be <0: virtual)
    const int jr    = imax(0, jlo_v);    // first real row

    __shared__ float rawbuf[2][W];
    __shared__ float uring[3][W];        // horizontal 3-sums of 3 input rows
    __shared__ float se[W + 8];          // s row; arr = col+8; [0..7] = -inf pad
    __shared__ float pA[W + 8];
    __shared__ float pB[W + 8];
    __shared__ double wsum[8];

    const int x   = threadIdx.x;         // column
    const int arr = x + 8;

    // column window size for avg branch (/289)
    const float cx = (float)(imin(W - 1, x + 8) - imax(0, x - 8) + 1) * (1.f / 289.f);

    if (x < 8) se[x] = NEG_INF;          // static left pad

    // rotating u-row pointers: pu_m1 = u(j-1), pu_0 = u(j), pu_p1 = target u(j+1)
    float* pu_m1 = uring[0];
    float* pu_0  = uring[1];
    float* pu_p1 = uring[2];

    // ---- prologue: build u(jr-1) -> pu_m1, u(jr) -> pu_0 ----
    if (jr >= 1) {
        float rv = im[(size_t)(jr - 1) * W + x];
        rawbuf[0][x] = rv;
        __syncthreads();
        pu_m1[x] = (x > 0 ? rawbuf[0][x - 1] : 0.f) + rv + (x < W - 1 ? rawbuf[0][x + 1] : 0.f);
    } else {
        pu_m1[x] = 0.f;                  // u(-1) = zero padding
    }
    {
        float rv = im[(size_t)jr * W + x];
        rawbuf[1][x] = rv;
        __syncthreads();
        pu_0[x] = (x > 0 ? rawbuf[1][x - 1] : 0.f) + rv + (x < W - 1 ? rawbuf[1][x + 1] : 0.f);
    }
    __syncthreads();                     // prologue complete; rawbuf reusable

    float accMax = 0.f, accSum = 0.f;
    float h_cur[17], S_prev[17];
#pragma unroll
    for (int r = 0; r < 17; ++r) { h_cur[r] = NEG_INF; S_prev[r] = NEG_INF; }

    int t = 0;
    for (int B = 0; B < (TMAX + 16) / 17; ++B) {
        float Pblk = NEG_INF;
#pragma unroll
        for (int p = 0; p < 17; ++p) {
            if (t < TMAX) {
                const int j = jlo_v + t;
                float h;
                if (j >= 0 && j < H) {
                    // ---- ingest input row j+1 ----
                    const int i = j + 1;
                    float rv = 0.f;
                    float* rbuf = rawbuf[t & 1];
                    if (i < H) {
                        rv = im[(size_t)i * W + x];
                        rbuf[x] = rv;
                    }
                    __syncthreads();     // raw ready; prev iter's se/pA/pB reads done
                    float u2v;
                    if (i < H)
                        u2v = (x > 0 ? rbuf[x - 1] : 0.f) + rv + (x < W - 1 ? rbuf[x + 1] : 0.f);
                    else
                        u2v = 0.f;       // u(H) = zero padding
                    pu_p1[x] = u2v;
                    // s row j (own-column reads of stable older u rows)
                    const float srv = (pu_m1[x] + pu_0[x] + u2v) * (1.f / 9.f);
                    se[arr] = srv;
                    __syncthreads();     // se ready

                    // ---- horizontal 17-max via log-doubling ----
                    float v2 = fmaxf(srv, se[imin(arr + 1, W + 7)]);
                    pA[arr] = v2;
                    float v2p = 0.f;
                    if (x < 8) { v2p = fmaxf(se[x], se[x + 1]); pA[x] = v2p; }
                    __syncthreads();
                    float v4 = fmaxf(v2, pA[imin(arr + 2, W + 7)]);
                    pB[arr] = v4;
                    float v4p = 0.f;
                    if (x < 8) { v4p = fmaxf(v2p, pA[x + 2]); pB[x] = v4p; }
                    __syncthreads();
                    float v8 = fmaxf(v4, pB[imin(arr + 4, W + 7)]);
                    pA[arr] = v8;
                    float v8p = 0.f;
                    if (x < 8) { v8p = fmaxf(v4p, pB[x + 4]); pA[x] = v8p; }
                    __syncthreads();
                    float v16 = fmaxf(v8, pA[imin(arr + 8, W + 7)]);
                    pB[arr] = v16;
                    if (x < 8) { pB[x] = fmaxf(v8p, pA[x + 8]); }
                    __syncthreads();
                    // centered: max over [x-8, x+8] clamped
                    h = fmaxf(pB[x], se[imin(arr + 8, W + 7)]);

                    // ---- avg branch: weighted sum of s ----
                    const int rlo = imax(y0, j - 8), rhi = imin(y1 - 1, j + 8);
                    accSum += srv * cx * (float)(rhi - rlo + 1);

                    // rotate u pointers (real rows only)
                    float* tmp = pu_m1; pu_m1 = pu_0; pu_0 = pu_p1; pu_p1 = tmp;
                } else {
                    h = NEG_INF;         // virtual row
                }

                // ---- vertical van Herk (registers only) ----
                h_cur[p] = h;
                Pblk = fmaxf(Pblk, h);
                if (t >= 16) {
                    // output y = y0 + t - 16; window = streamed rows [t-16, t]
                    float vmax = (p == 16) ? Pblk : fmaxf(S_prev[p + 1], Pblk);
                    accMax += vmax;
                }
                ++t;
            }
        }
        // suffix maxes of this block for the next block's outputs
        float s = NEG_INF;
#pragma unroll
        for (int r = 16; r >= 1; --r) { s = fmaxf(s, h_cur[r]); S_prev[r] = s; }
    }

    // ---- block reduction ----
    double v = (double)(accMax - accSum);
#pragma unroll
    for (int off = 32; off > 0; off >>= 1) v += __shfl_down(v, off, 64);
    const int lane = x & 63, wave = x >> 6;
    if (lane == 0) wsum[wave] = v;
    __syncthreads();
    if (x == 0) {
        double b = 0.0;
#pragma unroll
        for (int wv = 0; wv < 8; ++wv) b += wsum[wv];
        atomicAdd(acc, b);
    }
}

__global__ void finalize_kernel(const double* __restrict__ acc, float* __restrict__ out) {
    if (threadIdx.x == 0) {
        // total pixels across both tensors = 2*32*512*512 = 16777216
        out[0] = (float)(1.0 - acc[0] * (1.0 / 16777216.0));
    }
}

extern "C" void kernel_launch(void* const* d_in, const int* in_sizes, int n_in,
                              void* d_out, int out_size, void* d_ws, size_t ws_size,
                              hipStream_t stream) {
    const float* in0 = (const float*)d_in[0];
    const float* in1 = (const float*)d_in[1];
    float* out = (float*)d_out;
    double* acc = (double*)d_ws;

    zero_acc_kernel<<<1, 64, 0, stream>>>(acc);
    fused_kernel<<<dim3(NBANDS, 32, 2), 512, 0, stream>>>(in0, in1, acc);
    finalize_kernel<<<1, 64, 0, stream>>>(acc, out);
}

// Round 7
// 52.306 us; speedup vs baseline: 11.1326x; 1.9259x over previous
//
#include <hip/hip_runtime.h>

#define H 512
#define W 512
#define BAND 32
#define NBANDS (H / BAND)   // 16
#define NEG_INF (-3.402823466e38f)

__global__ void zero_acc_kernel(double* acc) {
    if (threadIdx.x == 0) acc[0] = 0.0;
}

// One block per (band of 32 output rows, image, tensor); 512 threads = 1 column.
// Streams s-rows in 3 segments of 16 (= 4 rounds of 4 rows). Per round:
//   - s rows via register u-chain (3 direct global loads, L1-hit), write to se[4][W]
//   - horizontal 17-max via log-doubling (steps 1,2,4,8) batched over 4 rows
//     -> 5 barriers per 4 rows
//   - vertical 17-max via van Herk, segment 16, single in-place 16-reg array
// Avg-pool branch collapses to weighted sum of s (closed-form border counts).
__global__ __launch_bounds__(512, 8) void fused_kernel(const float* __restrict__ in0,
                                                       const float* __restrict__ in1,
                                                       double* __restrict__ acc) {
    const int band = blockIdx.x;
    const int img  = blockIdx.y;
    const float* __restrict__ im = (blockIdx.z ? in1 : in0) + (size_t)img * H * W;

    const int y0    = band * BAND;
    const int y1    = y0 + BAND;
    const int jlo_v = y0 - 8;            // first streamed s-row (may be virtual)

    __shared__ float se[4][W];
    __shared__ float pA[4][W];
    __shared__ float pB[4][W];
    __shared__ double wsum[8];

    const int x   = threadIdx.x;
    const int xp1 = x + 1 < W ? x + 1 : W - 1;
    const int xp2 = x + 2 < W ? x + 2 : W - 1;
    const int xp4 = x + 4 < W ? x + 4 : W - 1;
    const int xp8 = x + 8 < W ? x + 8 : W - 1;
    const int xm8 = x >= 8 ? x - 8 : 0;

    // column window size for avg branch (/289)
    const int wlo = x - 8 > 0 ? x - 8 : 0;
    const int whi = x + 8 < W - 1 ? x + 8 : W - 1;
    const float cx = (float)(whi - wlo + 1) * (1.f / 289.f);

    // ---- prologue: u(jr-1), u(jr) in registers ----
    const int jr = jlo_v > 0 ? jlo_v : 0;
    float u_m1, u_0;
    {
        const int rm = jr - 1;
        if (rm >= 0) {
            const float* r = im + (size_t)rm * W;
            float b = r[x];
            float a = x > 0 ? r[x - 1] : 0.f;
            float c = x < W - 1 ? r[x + 1] : 0.f;
            u_m1 = a + b + c;
        } else {
            u_m1 = 0.f;                  // u(-1) = zero padding
        }
        const float* r = im + (size_t)jr * W;
        float b = r[x];
        float a = x > 0 ? r[x - 1] : 0.f;
        float c = x < W - 1 ? r[x + 1] : 0.f;
        u_0 = a + b + c;
    }

    float accMax = 0.f, accSum = 0.f;
    float arr[16];                       // van Herk: S_prev on read, h_cur on write

    for (int seg = 0; seg < 3; ++seg) {
        const bool emit = (seg != 0);    // outputs exist for t >= 16
        float Pblk = NEG_INF;
#pragma unroll
        for (int r4 = 0; r4 < 4; ++r4) {
            const int j0 = jlo_v + seg * 16 + r4 * 4;  // block-uniform
            float h4[4];
            if (j0 >= 0 && j0 < H) {     // uniform branch: barriers legal inside
                float srv[4], s8[4], vv[4];
                // stage 0: build 4 s-rows, write se, avg-branch accumulate
#pragma unroll
                for (int q = 0; q < 4; ++q) {
                    const int i = j0 + q + 1;
                    float u_p1 = 0.f;    // u(H) = zero padding
                    if (i < H) {
                        const float* r = im + (size_t)i * W;
                        float b = r[x];
                        float a = x > 0 ? r[x - 1] : 0.f;
                        float c = x < W - 1 ? r[x + 1] : 0.f;
                        u_p1 = a + b + c;
                    }
                    srv[q] = (u_m1 + u_0 + u_p1) * (1.f / 9.f);
                    u_m1 = u_0; u_0 = u_p1;
                    se[q][x] = srv[q];
                    const int j   = j0 + q;
                    const int rlo = j - 8 > y0 ? j - 8 : y0;
                    const int rhi = j + 8 < y1 - 1 ? j + 8 : y1 - 1;
                    accSum += srv[q] * cx * (float)(rhi - rlo + 1);
                }
                __syncthreads();         // se ready (also guards prev round's reads)
#pragma unroll
                for (int q = 0; q < 4; ++q) {
                    s8[q] = se[q][xp8];  // hoisted for final combine
                    vv[q] = fmaxf(srv[q], se[q][xp1]);   // v2 = max s[x..x+1]
                    pA[q][x] = vv[q];
                }
                __syncthreads();
#pragma unroll
                for (int q = 0; q < 4; ++q) {            // v4 = max s[x..x+3]
                    vv[q] = fmaxf(vv[q], pA[q][xp2]); pB[q][x] = vv[q];
                }
                __syncthreads();
#pragma unroll
                for (int q = 0; q < 4; ++q) {            // v8 = max s[x..x+7]
                    vv[q] = fmaxf(vv[q], pB[q][xp4]); pA[q][x] = vv[q];
                }
                __syncthreads();
#pragma unroll
                for (int q = 0; q < 4; ++q) {            // v16 = max s[x..x+15]
                    vv[q] = fmaxf(vv[q], pA[q][xp8]); pB[q][x] = vv[q];
                }
                __syncthreads();
                // h(x) = max s[x-8 .. x+8] (clamped):
                //   x>=8: v16(x-8) + s[x+8];  x<8: v8(0) + v8(x+1) covers [0..x+8]
#pragma unroll
                for (int q = 0; q < 4; ++q)
                    h4[q] = (x >= 8) ? fmaxf(pB[q][xm8], s8[q])
                                     : fmaxf(pA[q][0], pA[q][x + 1]);
            } else {
#pragma unroll
                for (int q = 0; q < 4; ++q) h4[q] = NEG_INF;  // virtual rows
            }
            // vertical van Herk ingest + emit (pure registers, static indices)
#pragma unroll
            for (int q = 0; q < 4; ++q) {
                const int p = r4 * 4 + q;                // static
                Pblk = fmaxf(Pblk, h4[q]);
                if (emit) accMax += fmaxf(arr[p], Pblk); // S_prev[p] vs prefix
                arr[p] = h4[q];                          // store h for suffix pass
            }
        }
        // segment end: in-place suffix transform arr[p] = max(h[p..15])
#pragma unroll
        for (int r = 14; r >= 0; --r) arr[r] = fmaxf(arr[r], arr[r + 1]);
    }

    // ---- block reduction ----
    double v = (double)(accMax - accSum);
#pragma unroll
    for (int off = 32; off > 0; off >>= 1) v += __shfl_down(v, off, 64);
    const int lane = x & 63, wave = x >> 6;
    if (lane == 0) wsum[wave] = v;
    __syncthreads();
    if (x == 0) {
        double b = 0.0;
#pragma unroll
        for (int wv = 0; wv < 8; ++wv) b += wsum[wv];
        atomicAdd(acc, b);
    }
}

__global__ void finalize_kernel(const double* __restrict__ acc, float* __restrict__ out) {
    if (threadIdx.x == 0) {
        // total pixels across both tensors = 2*32*512*512 = 16777216
        out[0] = (float)(1.0 - acc[0] * (1.0 / 16777216.0));
    }
}

extern "C" void kernel_launch(void* const* d_in, const int* in_sizes, int n_in,
                              void* d_out, int out_size, void* d_ws, size_t ws_size,
                              hipStream_t stream) {
    const float* in0 = (const float*)d_in[0];
    const float* in1 = (const float*)d_in[1];
    float* out = (float*)d_out;
    double* acc = (double*)d_ws;

    zero_acc_kernel<<<1, 64, 0, stream>>>(acc);
    fused_kernel<<<dim3(NBANDS, 32, 2), 512, 0, stream>>>(in0, in1, acc);
    finalize_kernel<<<1, 64, 0, stream>>>(acc, out);
}